// Round 16
// baseline (361.253 us; speedup 1.0000x reference)
//
#include <hip/hip_runtime.h>
#include <hip/hip_bf16.h>
#include <stdint.h>

#define B_SZ 8
#define L_SZ 2048
#define DM 768
#define DI 1536
#define DS 16
#define DR 48
#define M_SZ (B_SZ * L_SZ)   // 16384
#define N1 (2 * DI)          // 3072

#define NC 64                 // chunks per sequence
#define TC (L_SZ / NC)        // 32 steps per chunk
#define CH (B_SZ * DI)        // 12288 channels
#define KS 2                  // split-K slices for xdbl
#define NT2 (DM / 32)         // 24 K-tiles (BK=32) for gemm_xz
#define L2E 1.44269504088896f

typedef short short8 __attribute__((ext_vector_type(8)));
typedef float f32x4 __attribute__((ext_vector_type(4)));
typedef float f32x2 __attribute__((ext_vector_type(2)));

__device__ __forceinline__ ushort f2b(float f) {
  __hip_bfloat16 h = __float2bfloat16(f);
  return *reinterpret_cast<ushort*>(&h);
}
__device__ __forceinline__ float b2f(ushort u) {
  __hip_bfloat16 h;
  *reinterpret_cast<ushort*>(&h) = u;
  return __bfloat162float(h);
}
__device__ __forceinline__ ushort f2h(float f) {
  _Float16 h = (_Float16)f;
  return *reinterpret_cast<ushort*>(&h);
}
__device__ __forceinline__ float h2f(ushort u) {
  _Float16 h;
  *reinterpret_cast<ushort*>(&h) = u;
  return (float)h;
}

__device__ __forceinline__ void gl16(const ushort* g, ushort* l) {
  __builtin_amdgcn_global_load_lds(
      (const __attribute__((address_space(1))) void*)g,
      (__attribute__((address_space(3))) void*)l, 16, 0, 0);
}

// ---------------- merged prep: cast hidden, transpose W_in, cast W_x, pad W_dt ------------

__global__ __launch_bounds__(256) void prep_all(const float4* __restrict__ hs4,
                                                const float* __restrict__ w_in,
                                                const float* __restrict__ wx_f,
                                                const float* __restrict__ wdt_f,
                                                ushort4* __restrict__ A1,
                                                ushort* __restrict__ wt,
                                                ushort* __restrict__ wx_b,
                                                ushort* __restrict__ wdt_p) {
  const int n4 = M_SZ * DM / 4;
  const int nT = 3072 * 96;
  const int nwx = 80 * DI;
  const int nwdt = DI * 64;
  int idx = blockIdx.x * 256 + threadIdx.x;
  if (idx < n4) {
    float4 v = hs4[idx];
    ushort4 o;
    o.x = f2b(v.x); o.y = f2b(v.y); o.z = f2b(v.z); o.w = f2b(v.w);
    A1[idx] = o;
  } else if (idx < n4 + nT) {
    int j = idx - n4;
    int n = j % 3072;
    int kb = (j / 3072) * 8;
    short8 o;
#pragma unroll
    for (int q = 0; q < 8; ++q) o[q] = (short)f2b(w_in[(size_t)(kb + q) * 3072 + n]);
    *(short8*)(wt + (size_t)n * DM + kb) = o;
  } else if (idx < n4 + nT + nwx) {
    int j = idx - n4 - nT;
    wx_b[j] = f2b(wx_f[j]);
  } else if (idx < n4 + nT + nwx + nwdt) {
    int j = idx - n4 - nT - nwx;
    int col = j >> 6, k = j & 63;
    wdt_p[j] = (k < DR) ? f2b(wdt_f[col * DR + k]) : (ushort)0;
  }
}

// ---------------- main GEMM: xz = A1(16384x768) @ W_in  (256x256 tile) -------------------
// R16: single barrier per K-tile + cross-phase fragment prefetch.  afr1's ds_reads issue
// before the q0 MFMA cluster (latency hides under MFMA); next-tile bfr/afr0 reads issue
// after the barrier, before the q1 cluster (hides under q1).  Explicit lgkmcnt(0) before
// the barrier guarantees all b0 reads complete before b0 is re-staged.  Triple-buffered
// BK=32, counted vmcnt(4), fragment-major LDS, by-major-within-bx ordering (all proven).
// R13 lesson: acc = 128 AGPRs -> keep __launch_bounds__(512, 1).

__global__ __launch_bounds__(512, 1) void gemm_xz(const ushort* __restrict__ A,
                                                  const ushort* __restrict__ Bt,
                                                  ushort* __restrict__ xout,
                                                  ushort* __restrict__ gateout) {
  __shared__ ushort lds[49152];  // 96 KiB: 3 buffers x 16384 ushorts (32 chunks x 1 KB)

  const int t = threadIdx.x;
  const int lane = t & 63;
  const int wid = t >> 6;
  const int wm = wid >> 2, wn = wid & 3;
  const int r = lane & 15, hi = lane >> 4;

  const int g = blockIdx.x;        // 768 blocks
  const int xcd = g & 7;
  const int local = g >> 3;        // 0..95
  const int bx = xcd * 8 + local / 12;   // 64 M-blocks, 8 per XCD
  const int by = local % 12;             // 12 N-blocks, consecutive per bx
  const int bm = bx * 256;
  const int bn = by * 256;

  const ushort* gsrc[4];
  int ldso[4];
#pragma unroll
  for (int i = 0; i < 4; ++i) {
    int c = wid * 4 + i;
    if (c < 16)
      gsrc[i] = A + (size_t)(bm + c * 16 + r) * DM + hi * 8;
    else
      gsrc[i] = Bt + (size_t)(bn + (c - 16) * 16 + r) * DM + hi * 8;
    ldso[i] = c * 512;
  }

  f32x4 acc[8][4];
#pragma unroll
  for (int m = 0; m < 8; ++m)
#pragma unroll
    for (int n = 0; n < 4; ++n) acc[m][n] = f32x4{0.f, 0.f, 0.f, 0.f};

  ushort* b0 = lds;
  ushort* b1 = lds + 16384;
  ushort* b2 = lds + 32768;

  // prologue: stage tile 0 -> b0, tile 1 -> b1
#pragma unroll
  for (int i = 0; i < 4; ++i) gl16(gsrc[i], b0 + ldso[i]);
#pragma unroll
  for (int i = 0; i < 4; ++i) gl16(gsrc[i] + 32, b1 + ldso[i]);
  asm volatile("s_waitcnt vmcnt(4)" ::: "memory");  // tile 0 landed (own); barrier collects
  __builtin_amdgcn_s_barrier();

  // preload tile-0 fragments
  short8 bfr[4], afr0[4], afr1[4], bfr_n[4], afr0_n[4];
#pragma unroll
  for (int n = 0; n < 4; ++n)
    bfr[n] = *(const short8*)&b0[(16 + wn * 4 + n) * 512 + lane * 8];
#pragma unroll
  for (int m = 0; m < 4; ++m)
    afr0[m] = *(const short8*)&b0[(wm * 8 + m) * 512 + lane * 8];

  for (int kt = 0; kt < NT2; ++kt) {
    const bool stage = (kt + 2 < NT2);
    const bool more = (kt + 1 < NT2);
    const int koff = (kt + 2) * 32;

    if (stage) {
#pragma unroll
      for (int i = 0; i < 4; ++i) gl16(gsrc[i] + koff, b2 + ldso[i]);
    }
    // q1 fragments of current tile -- latency hides under q0 MFMA
#pragma unroll
    for (int m = 0; m < 4; ++m)
      afr1[m] = *(const short8*)&b0[(wm * 8 + 4 + m) * 512 + lane * 8];

    __builtin_amdgcn_s_setprio(1);
#pragma unroll
    for (int m = 0; m < 4; ++m)
#pragma unroll
      for (int n = 0; n < 4; ++n)
        acc[m][n] = __builtin_amdgcn_mfma_f32_16x16x32_bf16(afr0[m], bfr[n], acc[m][n], 0, 0, 0);
    __builtin_amdgcn_s_setprio(0);

    if (stage)
      asm volatile("s_waitcnt vmcnt(4)" ::: "memory");  // counted: tile kt+1 landed (own)
    else
      asm volatile("s_waitcnt vmcnt(0)" ::: "memory");  // tail drain
    asm volatile("s_waitcnt lgkmcnt(0)" ::: "memory");  // all b0 reads complete pre-barrier
    asm volatile("s_barrier" ::: "memory");             // tile kt+1 landed for ALL waves

    if (more) {
      // next-tile fragments from b1 -- latency hides under q1 MFMA
#pragma unroll
      for (int n = 0; n < 4; ++n)
        bfr_n[n] = *(const short8*)&b1[(16 + wn * 4 + n) * 512 + lane * 8];
#pragma unroll
      for (int m = 0; m < 4; ++m)
        afr0_n[m] = *(const short8*)&b1[(wm * 8 + m) * 512 + lane * 8];
    }

    __builtin_amdgcn_s_setprio(1);
#pragma unroll
    for (int m = 0; m < 4; ++m)
#pragma unroll
      for (int n = 0; n < 4; ++n)
        acc[4 + m][n] =
            __builtin_amdgcn_mfma_f32_16x16x32_bf16(afr1[m], bfr[n], acc[4 + m][n], 0, 0, 0);
    __builtin_amdgcn_s_setprio(0);

    ushort* tmp = b0; b0 = b1; b1 = b2; b2 = tmp;
#pragma unroll
    for (int i = 0; i < 4; ++i) { bfr[i] = bfr_n[i]; afr0[i] = afr0_n[i]; }
  }

  const bool isx = (bn < DI);
  ushort* outp = isx ? xout : gateout;
  const int cbase = bn - (isx ? 0 : DI) + wn * 64;
#pragma unroll
  for (int mf = 0; mf < 8; ++mf)
#pragma unroll
    for (int nf = 0; nf < 4; ++nf) {
      int col = cbase + nf * 16 + r;
#pragma unroll
      for (int j = 0; j < 4; ++j) {
        int row = bm + wm * 128 + mf * 16 + hi * 4 + j;
        float v = acc[mf][nf][j];
        if (!isx) v = v / (1.f + __expf(-v));  // silu(res) fused
        outp[(size_t)row * DI + col] = f2b(v);
      }
    }
}

// ---------------- FUSED depthwise conv+SiLU + x_dbl split-K GEMM (KS=2) ------------------

__global__ __launch_bounds__(256) void xdbl_conv(const ushort* __restrict__ xp,
                                                 const float* __restrict__ cw,
                                                 const float* __restrict__ cb,
                                                 const ushort* __restrict__ wx,
                                                 ushort* __restrict__ xc,
                                                 float* __restrict__ xdp) {
  __shared__ ushort Af[32 * 544];  // 34 KB

  const int tid = threadIdx.x;
  const int row0 = blockIdx.x * 64;
  const int ks = blockIdx.y;       // 0..1

  const int lane = tid & 63, wid = tid >> 6;
  const int r = lane & 15, hi = lane >> 4;
  const int row0w = row0 + wid * 16;

  f32x4 acc[5];
#pragma unroll
  for (int n = 0; n < 5; ++n) acc[n] = f32x4{0.f, 0.f, 0.f, 0.f};

  const int rg = tid >> 5;          // 0..7 row-group (8 rows each)
  const int c8 = tid & 31;          // col8 0..31
  const int col_loc = c8 * 8;
  const int chunkc = col_loc >> 5;  // 0..7
  const int hi_w = (col_loc & 31) >> 3;

  for (int sl = 0; sl < 3; ++sl) {
    const int kbeg = ks * 768 + sl * 256;
    if (sl) __syncthreads();  // protect prior-slice Af reads

    {
      const int col = kbeg + col_loc;
      float4 cwv[8];
      float cbv[8];
#pragma unroll
      for (int e = 0; e < 8; ++e) {
        cwv[e] = *(const float4*)(cw + (size_t)(col + e) * 4);
        cbv[e] = cb[col + e];
      }
      short8 z8 = {0, 0, 0, 0, 0, 0, 0, 0};
#pragma unroll
      for (int j = 0; j < 8; ++j) {
        int row = row0 + rg * 8 + j;
        int l = row & (L_SZ - 1);
        const ushort* base = xp + (size_t)row * DI + col;
        short8 x0 = *(const short8*)base;
        short8 xm1 = (l >= 1) ? *(const short8*)(base - DI) : z8;
        short8 xm2 = (l >= 2) ? *(const short8*)(base - 2 * DI) : z8;
        short8 xm3 = (l >= 3) ? *(const short8*)(base - 3 * DI) : z8;
        short8 o;
#pragma unroll
        for (int e = 0; e < 8; ++e) {
          float4 w = cwv[e];
          float a = cbv[e] + w.x * b2f((ushort)xm3[e]) + w.y * b2f((ushort)xm2[e]) +
                    w.z * b2f((ushort)xm1[e]) + w.w * b2f((ushort)x0[e]);
          o[e] = (short)f2b(a / (1.f + __expf(-a)));
        }
        *(short8*)(xc + (size_t)row * DI + col) = o;
        int row_loc = rg * 8 + j;
        int chunk = (row_loc >> 4) * 8 + chunkc;
        int lane_t = (hi_w << 4) | (row_loc & 15);
        int slot = lane_t ^ (chunk & 7);
        *(short8*)&Af[chunk * 544 + slot * 8] = o;
      }
    }
    __syncthreads();

#pragma unroll
    for (int k0 = 0; k0 < 8; ++k0) {
      int chunk = wid * 8 + k0;
      short8 a = *(const short8*)&Af[chunk * 544 + ((lane ^ (chunk & 7)) * 8)];
      const int kk = kbeg + k0 * 32;
#pragma unroll
      for (int n = 0; n < 5; ++n) {
        short8 b = *(const short8*)(wx + (size_t)(n * 16 + r) * DI + kk + hi * 8);
        acc[n] = __builtin_amdgcn_mfma_f32_16x16x32_bf16(a, b, acc[n], 0, 0, 0);
      }
    }
  }

  float* op = xdp + (size_t)ks * M_SZ * 80;
#pragma unroll
  for (int n = 0; n < 5; ++n)
#pragma unroll
    for (int j = 0; j < 4; ++j)
      op[(size_t)(row0w + hi * 4 + j) * 80 + n * 16 + r] = acc[n][j];
}

// ---------------- dt = softplus(x_dbl[:, :48] @ W_dt^T + b_dt) -> fp16 -------------------

__device__ __forceinline__ short8 pack8f(const float* p) {
  short8 v;
#pragma unroll
  for (int i = 0; i < 8; ++i) v[i] = (short)f2b(p[i]);
  return v;
}

__global__ __launch_bounds__(256) void dt_gemm(const float* __restrict__ xdp,
                                               const ushort* __restrict__ wdtp,
                                               const float* __restrict__ bdt,
                                               ushort* __restrict__ dt) {
  int wave = blockIdx.x * 4 + (threadIdx.x >> 6);
  int lane = threadIdx.x & 63;
  int r = lane & 15, hi = lane >> 4;
  int row0 = wave * 16;

  const float* p0 = xdp + (size_t)(row0 + r) * 80 + hi * 8;
  const float* p1 = p0 + (size_t)M_SZ * 80;

  float atmp[8];
  float4 q0 = *(const float4*)p0, q1 = *(const float4*)(p0 + 4);
  float4 s0 = *(const float4*)p1, s1 = *(const float4*)(p1 + 4);
  atmp[0] = q0.x + s0.x; atmp[1] = q0.y + s0.y; atmp[2] = q0.z + s0.z; atmp[3] = q0.w + s0.w;
  atmp[4] = q1.x + s1.x; atmp[5] = q1.y + s1.y; atmp[6] = q1.z + s1.z; atmp[7] = q1.w + s1.w;
  short8 a0 = pack8f(atmp);
  short8 a1 = {0, 0, 0, 0, 0, 0, 0, 0};
  if (hi < 2) {
    const float* q0p = xdp + (size_t)(row0 + r) * 80 + 32 + hi * 8;
    const float* q1p = q0p + (size_t)M_SZ * 80;
    float4 u0 = *(const float4*)q0p, u1 = *(const float4*)(q0p + 4);
    float4 v0 = *(const float4*)q1p, v1 = *(const float4*)(q1p + 4);
    atmp[0] = u0.x + v0.x; atmp[1] = u0.y + v0.y; atmp[2] = u0.z + v0.z; atmp[3] = u0.w + v0.w;
    atmp[4] = u1.x + v1.x; atmp[5] = u1.y + v1.y; atmp[6] = u1.z + v1.z; atmp[7] = u1.w + v1.w;
    a1 = pack8f(atmp);
  }

  for (int nb = blockIdx.y * 6; nb < blockIdx.y * 6 + 6; ++nb) {
    int c0 = nb * 64;
    f32x4 acc[4];
#pragma unroll
    for (int n = 0; n < 4; ++n) acc[n] = f32x4{0.f, 0.f, 0.f, 0.f};
#pragma unroll
    for (int n = 0; n < 4; ++n) {
      const ushort* wp = wdtp + (size_t)(c0 + n * 16 + r) * 64;
      short8 b0 = *(const short8*)(wp + hi * 8);
      short8 b1 = *(const short8*)(wp + 32 + hi * 8);
      acc[n] = __builtin_amdgcn_mfma_f32_16x16x32_bf16(a0, b0, acc[n], 0, 0, 0);
      acc[n] = __builtin_amdgcn_mfma_f32_16x16x32_bf16(a1, b1, acc[n], 0, 0, 0);
    }
#pragma unroll
    for (int n = 0; n < 4; ++n)
#pragma unroll
      for (int j = 0; j < 4; ++j) {
        int col = c0 + n * 16 + r;
        float z = acc[n][j] + bdt[col];
        float sp = (z > 20.f) ? z : __logf(1.f + __expf(z));
        dt[(size_t)(row0 + hi * 4 + j) * DI + col] = f2h(sp);
      }
  }
}

// ---------------- chunked selective scan (NC=64, depth-2 prefetch, pk math) --------------

__global__ __launch_bounds__(256) void scan_pass1(const ushort* __restrict__ dt,
                                                  const ushort* __restrict__ xc,
                                                  const float* __restrict__ xdp,
                                                  const float* __restrict__ A_log,
                                                  float* __restrict__ hend,
                                                  float* __restrict__ sumdt) {
  const int d = blockIdx.x * 256 + threadIdx.x;
  const int c = blockIdx.y, b = blockIdx.z;
  const int t0 = c * TC;

  __shared__ float Bs[TC * 16];
  for (int i = threadIdx.x; i < TC * 16; i += 256) {
    int tt = i >> 4, s = i & 15;
    size_t row = ((size_t)(b * L_SZ + t0 + tt)) * 80 + DR + s;
    Bs[i] = xdp[row] + xdp[(size_t)M_SZ * 80 + row];
  }

  f32x2 a2[8];
  const float4* al4 = (const float4*)(A_log + (size_t)d * DS);
#pragma unroll
  for (int q = 0; q < 4; ++q) {
    float4 v = al4[q];
    a2[2 * q] = f32x2{-__expf(v.x) * L2E, -__expf(v.y) * L2E};
    a2[2 * q + 1] = f32x2{-__expf(v.z) * L2E, -__expf(v.w) * L2E};
  }

  __syncthreads();

  f32x2 h2[8];
#pragma unroll
  for (int q = 0; q < 8; ++q) h2[q] = f32x2{0.f, 0.f};
  float sd = 0.f;

  const ushort* dtp = dt + ((size_t)b * L_SZ + t0) * DI + d;
  const ushort* xp = xc + ((size_t)b * L_SZ + t0) * DI + d;

  ushort dt0 = dtp[0], dt1 = dtp[DI];
  ushort xu0 = xp[0], xu1 = xp[DI];
  dtp += 2 * (size_t)DI; xp += 2 * (size_t)DI;
  const f32x4* bp4 = (const f32x4*)Bs;
#pragma unroll 2
  for (int tt = 0; tt < TC; ++tt) {
    ushort dtu = dt0, xu = xu0;
    dt0 = dt1; xu0 = xu1;
    dt1 = *dtp; xu1 = *xp;
    dtp += DI; xp += DI;
    float dtv = h2f(dtu);
    float xv = b2f(xu);
    sd += dtv;
    float dx = dtv * xv;
    f32x2 dts = f32x2{dtv, dtv};
    f32x2 dxs = f32x2{dx, dx};
#pragma unroll
    for (int q4 = 0; q4 < 4; ++q4) {
      f32x4 bq = bp4[q4];
#pragma unroll
      for (int hq = 0; hq < 2; ++hq) {
        int q = q4 * 2 + hq;
        f32x2 bv = f32x2{bq[2 * hq], bq[2 * hq + 1]};
        f32x2 arg, t2;
        asm("v_pk_mul_f32 %0, %1, %2" : "=v"(arg) : "v"(dts), "v"(a2[q]));
        float e0, e1;
        asm("v_exp_f32 %0, %1" : "=v"(e0) : "v"(arg[0]));
        asm("v_exp_f32 %0, %1" : "=v"(e1) : "v"(arg[1]));
        asm("v_pk_mul_f32 %0, %1, %2" : "=v"(t2) : "v"(dxs), "v"(bv));
        h2[q][0] = __builtin_fmaf(e0, h2[q][0], t2[0]);
        h2[q][1] = __builtin_fmaf(e1, h2[q][1], t2[1]);
      }
    }
    bp4 += 4;
  }

  const size_t ch = (size_t)b * DI + d;
  sumdt[ch * NC + c] = sd;
  f32x2* hp = (f32x2*)&hend[((size_t)c * CH + ch) * 16];
#pragma unroll
  for (int q = 0; q < 8; ++q) hp[q] = h2[q];
}

// pass2: in-place hbuf (reads hend[c], overwrites with hstart[c])

__global__ __launch_bounds__(256) void scan_pass2(const float* __restrict__ A_log,
                                                  const float* __restrict__ sumdt,
                                                  float* __restrict__ hbuf) {
  int idx = blockIdx.x * 256 + threadIdx.x;
  int ch = idx >> 4, s = idx & 15;
  int d = ch % DI;
  float A = -__expf(A_log[d * DS + s]);
  float h = 0.f;
  for (int c = 0; c < NC; ++c) {
    float* p = &hbuf[((size_t)c * CH + ch) * 16 + s];
    float he = *p;
    *p = h;
    float sd = sumdt[(size_t)ch * NC + c];
    h = __expf(A * sd) * h + he;
  }
}

__global__ __launch_bounds__(256) void scan_pass3(const ushort* __restrict__ dt,
                                                  const ushort* __restrict__ xc,
                                                  const float* __restrict__ xdp,
                                                  const ushort* __restrict__ gateb,
                                                  const float* __restrict__ A_log,
                                                  const float* __restrict__ Dp,
                                                  const float* __restrict__ hstart,
                                                  float* __restrict__ out) {
  const int d = blockIdx.x * 256 + threadIdx.x;
  const int c = blockIdx.y, b = blockIdx.z;
  const int t0 = c * TC;

  __shared__ float Bs[TC * 16];
  __shared__ float Cs[TC * 16];
  for (int i = threadIdx.x; i < TC * 16; i += 256) {
    int tt = i >> 4, s = i & 15;
    size_t row = ((size_t)(b * L_SZ + t0 + tt)) * 80;
    Bs[i] = xdp[row + DR + s] + xdp[(size_t)M_SZ * 80 + row + DR + s];
    Cs[i] = xdp[row + DR + DS + s] + xdp[(size_t)M_SZ * 80 + row + DR + DS + s];
  }

  f32x2 a2[8];
  const float4* al4 = (const float4*)(A_log + (size_t)d * DS);
#pragma unroll
  for (int q = 0; q < 4; ++q) {
    float4 v = al4[q];
    a2[2 * q] = f32x2{-__expf(v.x) * L2E, -__expf(v.y) * L2E};
    a2[2 * q + 1] = f32x2{-__expf(v.z) * L2E, -__expf(v.w) * L2E};
  }
  const float Dpv = Dp[d];

  const size_t ch = (size_t)b * DI + d;
  f32x2 h2[8];
  const f32x2* hp = (const f32x2*)&hstart[((size_t)c * CH + ch) * 16];
#pragma unroll
  for (int q = 0; q < 8; ++q) h2[q] = hp[q];

  __syncthreads();

  const ushort* dtp = dt + ((size_t)b * L_SZ + t0) * DI + d;
  const ushort* xp = xc + ((size_t)b * L_SZ + t0) * DI + d;
  const ushort* gp = gateb + ((size_t)b * L_SZ + t0) * DI + d;
  float* op = out + ((size_t)b * L_SZ + t0) * DI + d;

  ushort dt0 = dtp[0], dt1 = dtp[DI];
  ushort xu0 = xp[0], xu1 = xp[DI];
  ushort gu0 = gp[0], gu1 = gp[DI];
  dtp += 2 * (size_t)DI; xp += 2 * (size_t)DI; gp += 2 * (size_t)DI;
  const f32x4* bp4 = (const f32x4*)Bs;
  const f32x4* cp4 = (const f32x4*)Cs;
#pragma unroll 2
  for (int tt = 0; tt < TC; ++tt) {
    ushort dtu = dt0, xu = xu0, gu = gu0;
    dt0 = dt1; xu0 = xu1; gu0 = gu1;
    dt1 = *dtp; xu1 = *xp; gu1 = *gp;
    dtp += DI; xp += DI; gp += DI;
    float dtv = h2f(dtu);
    float xv = b2f(xu);
    float gv = b2f(gu);
    float dx = dtv * xv;
    f32x2 dts = f32x2{dtv, dtv};
    f32x2 dxs = f32x2{dx, dx};
    f32x2 ya = f32x2{0.f, 0.f}, yb = f32x2{0.f, 0.f};
#pragma unroll
    for (int q4 = 0; q4 < 4; ++q4) {
      f32x4 bq = bp4[q4];
      f32x4 cq = cp4[q4];
#pragma unroll
      for (int hq = 0; hq < 2; ++hq) {
        int q = q4 * 2 + hq;
        f32x2 bv = f32x2{bq[2 * hq], bq[2 * hq + 1]};
        f32x2 cv = f32x2{cq[2 * hq], cq[2 * hq + 1]};
        f32x2 arg, t2;
        asm("v_pk_mul_f32 %0, %1, %2" : "=v"(arg) : "v"(dts), "v"(a2[q]));
        float e0, e1;
        asm("v_exp_f32 %0, %1" : "=v"(e0) : "v"(arg[0]));
        asm("v_exp_f32 %0, %1" : "=v"(e1) : "v"(arg[1]));
        asm("v_pk_mul_f32 %0, %1, %2" : "=v"(t2) : "v"(dxs), "v"(bv));
        h2[q][0] = __builtin_fmaf(e0, h2[q][0], t2[0]);
        h2[q][1] = __builtin_fmaf(e1, h2[q][1], t2[1]);
        if (hq)
          asm("v_pk_fma_f32 %0, %1, %2, %0" : "+v"(yb) : "v"(h2[q]), "v"(cv));
        else
          asm("v_pk_fma_f32 %0, %1, %2, %0" : "+v"(ya) : "v"(h2[q]), "v"(cv));
      }
    }
    bp4 += 4; cp4 += 4;
    float y = (ya[0] + ya[1]) + (yb[0] + yb[1]);
    op[0] = (y + xv * Dpv) * gv;
    op += DI;
  }
}

// ---------------- launch ----------------

extern "C" void kernel_launch(void* const* d_in, const int* in_sizes, int n_in,
                              void* d_out, int out_size, void* d_ws, size_t ws_size,
                              hipStream_t stream) {
  const float* hs     = (const float*)d_in[0];
  const float* W_in   = (const float*)d_in[1];
  const float* conv_w = (const float*)d_in[2];
  const float* conv_b = (const float*)d_in[3];
  const float* W_x    = (const float*)d_in[4];
  const float* W_dt   = (const float*)d_in[5];
  const float* b_dt   = (const float*)d_in[6];
  const float* A_log  = (const float*)d_in[7];
  const float* D_par  = (const float*)d_in[8];
  float* out = (float*)d_out;
  char* ws = (char*)d_ws;

  size_t o = 0;
  ushort* A1   = (ushort*)(ws + o); o += (size_t)M_SZ * DM * 2;        // 25.2 MB
  ushort* Wt1  = (ushort*)(ws + o); o += (size_t)N1 * DM * 2;          // 4.7 MB
  ushort* xpre = (ushort*)(ws + o); o += (size_t)M_SZ * DI * 2;        // 50.3 MB
  ushort* gate = (ushort*)(ws + o); o += (size_t)M_SZ * DI * 2;        // 50.3 MB (silu(res))
  ushort* xcv  = (ushort*)(ws + o); o += (size_t)M_SZ * DI * 2;        // 50.3 MB
  ushort* dtb  = (ushort*)(ws + o); o += (size_t)M_SZ * DI * 2;        // 50.3 MB (fp16)
  float*  xdp  = (float*)(ws + o);  o += (size_t)KS * M_SZ * 80 * 4;   // 10.5 MB
  ushort* Wxb  = (ushort*)(ws + o); o += (size_t)80 * DI * 2;          // 0.25 MB
  ushort* Wdtp = (ushort*)(ws + o); o += (size_t)DI * 64 * 2;          // 0.2 MB
  if (ws_size < o) return;

  // scan scratch aliases the dead A1/Wt1/xpre region (53.4 MB < 80.2 MB)
  float* hbuf  = (float*)(ws + 0);
  float* sumdt = (float*)(ws + (size_t)NC * CH * 16 * 4);

  const int nprep = M_SZ * DM / 4 + 3072 * 96 + 80 * DI + DI * 64;
  prep_all<<<dim3((nprep + 255) / 256), dim3(256), 0, stream>>>(
      (const float4*)hs, W_in, W_x, W_dt, (ushort4*)A1, Wt1, Wxb, Wdtp);

  gemm_xz<<<dim3((M_SZ / 256) * (N1 / 256)), dim3(512), 0, stream>>>(A1, Wt1, xpre, gate);

  xdbl_conv<<<dim3(M_SZ / 64, KS), dim3(256), 0, stream>>>(xpre, conv_w, conv_b, Wxb,
                                                           xcv, xdp);

  dt_gemm<<<dim3(M_SZ / 64, 4), dim3(256), 0, stream>>>(xdp, Wdtp, b_dt, dtb);

  scan_pass1<<<dim3(DI / 256, NC, B_SZ), dim3(256), 0, stream>>>(dtb, xcv, xdp, A_log, hbuf, sumdt);
  scan_pass2<<<dim3(CH * 16 / 256), dim3(256), 0, stream>>>(A_log, sumdt, hbuf);
  scan_pass3<<<dim3(DI / 256, NC, B_SZ), dim3(256), 0, stream>>>(dtb, xcv, xdp, gate,
                                                                 A_log, D_par, hbuf, out);
}

// Round 17
// 359.206 us; speedup vs baseline: 1.0057x; 1.0057x over previous
//
#include <hip/hip_runtime.h>
#include <hip/hip_bf16.h>
#include <stdint.h>

#define B_SZ 8
#define L_SZ 2048
#define DM 768
#define DI 1536
#define DS 16
#define DR 48
#define M_SZ (B_SZ * L_SZ)   // 16384
#define N1 (2 * DI)          // 3072

#define NC 64                 // chunks per sequence
#define TC (L_SZ / NC)        // 32 steps per chunk
#define CH (B_SZ * DI)        // 12288 channels
#define KS 2                  // split-K slices for xdbl
#define NT2 (DM / 32)         // 24 K-tiles (BK=32) for gemm_xz
#define L2E 1.44269504088896f

typedef short short8 __attribute__((ext_vector_type(8)));
typedef float f32x4 __attribute__((ext_vector_type(4)));
typedef float f32x2 __attribute__((ext_vector_type(2)));

__device__ __forceinline__ ushort f2b(float f) {
  __hip_bfloat16 h = __float2bfloat16(f);
  return *reinterpret_cast<ushort*>(&h);
}
__device__ __forceinline__ float b2f(ushort u) {
  __hip_bfloat16 h;
  *reinterpret_cast<ushort*>(&h) = u;
  return __bfloat162float(h);
}
__device__ __forceinline__ ushort f2h(float f) {
  _Float16 h = (_Float16)f;
  return *reinterpret_cast<ushort*>(&h);
}
__device__ __forceinline__ float h2f(ushort u) {
  _Float16 h;
  *reinterpret_cast<ushort*>(&h) = u;
  return (float)h;
}

__device__ __forceinline__ void gl16(const ushort* g, ushort* l) {
  __builtin_amdgcn_global_load_lds(
      (const __attribute__((address_space(1))) void*)g,
      (__attribute__((address_space(3))) void*)l, 16, 0, 0);
}

// ---------------- merged prep: cast hidden, transpose W_in, cast W_x, pad W_dt ------------

__global__ __launch_bounds__(256) void prep_all(const float4* __restrict__ hs4,
                                                const float* __restrict__ w_in,
                                                const float* __restrict__ wx_f,
                                                const float* __restrict__ wdt_f,
                                                ushort4* __restrict__ A1,
                                                ushort* __restrict__ wt,
                                                ushort* __restrict__ wx_b,
                                                ushort* __restrict__ wdt_p) {
  const int n4 = M_SZ * DM / 4;
  const int nT = 3072 * 96;
  const int nwx = 80 * DI;
  const int nwdt = DI * 64;
  int idx = blockIdx.x * 256 + threadIdx.x;
  if (idx < n4) {
    float4 v = hs4[idx];
    ushort4 o;
    o.x = f2b(v.x); o.y = f2b(v.y); o.z = f2b(v.z); o.w = f2b(v.w);
    A1[idx] = o;
  } else if (idx < n4 + nT) {
    int j = idx - n4;
    int n = j % 3072;
    int kb = (j / 3072) * 8;
    short8 o;
#pragma unroll
    for (int q = 0; q < 8; ++q) o[q] = (short)f2b(w_in[(size_t)(kb + q) * 3072 + n]);
    *(short8*)(wt + (size_t)n * DM + kb) = o;
  } else if (idx < n4 + nT + nwx) {
    int j = idx - n4 - nT;
    wx_b[j] = f2b(wx_f[j]);
  } else if (idx < n4 + nT + nwx + nwdt) {
    int j = idx - n4 - nT - nwx;
    int col = j >> 6, k = j & 63;
    wdt_p[j] = (k < DR) ? f2b(wdt_f[col * DR + k]) : (ushort)0;
  }
}

// ---------------- main GEMM: xz = A1(16384x768) @ W_in  (256x256 tile) -------------------
// R9/R12 proven config (113 us, settled optimum): fragment-major LDS, triple-buffered
// BK=32, counted vmcnt(4), by-major-within-bx ordering (A-panel L2-resident, FETCH ~85MB).
// Closed lines: 8-phase variants (R5/R6/R16) 113-140; BN=128 (R8/R10) worse; 2 blocks/CU
// impossible (R13: acc=128 AGPRs spills at min-waves>1 -> keep __launch_bounds__(512,1)).

__global__ __launch_bounds__(512, 1) void gemm_xz(const ushort* __restrict__ A,
                                                  const ushort* __restrict__ Bt,
                                                  ushort* __restrict__ xout,
                                                  ushort* __restrict__ gateout) {
  __shared__ ushort lds[49152];  // 96 KiB: 3 buffers x 16384 ushorts (32 chunks x 1 KB)

  const int t = threadIdx.x;
  const int lane = t & 63;
  const int wid = t >> 6;
  const int wm = wid >> 2, wn = wid & 3;
  const int r = lane & 15, hi = lane >> 4;

  const int g = blockIdx.x;        // 768 blocks
  const int xcd = g & 7;
  const int local = g >> 3;        // 0..95
  const int bx = xcd * 8 + local / 12;   // 64 M-blocks, 8 per XCD
  const int by = local % 12;             // 12 N-blocks, consecutive per bx
  const int bm = bx * 256;
  const int bn = by * 256;

  const ushort* gsrc[4];
  int ldso[4];
#pragma unroll
  for (int i = 0; i < 4; ++i) {
    int c = wid * 4 + i;
    if (c < 16)
      gsrc[i] = A + (size_t)(bm + c * 16 + r) * DM + hi * 8;
    else
      gsrc[i] = Bt + (size_t)(bn + (c - 16) * 16 + r) * DM + hi * 8;
    ldso[i] = c * 512;
  }

  f32x4 acc[8][4];
#pragma unroll
  for (int m = 0; m < 8; ++m)
#pragma unroll
    for (int n = 0; n < 4; ++n) acc[m][n] = f32x4{0.f, 0.f, 0.f, 0.f};

  ushort* b0 = lds;
  ushort* b1 = lds + 16384;
  ushort* b2 = lds + 32768;

#pragma unroll
  for (int i = 0; i < 4; ++i) gl16(gsrc[i], b0 + ldso[i]);
#pragma unroll
  for (int i = 0; i < 4; ++i) gl16(gsrc[i] + 32, b1 + ldso[i]);
  asm volatile("s_waitcnt vmcnt(4)" ::: "memory");
  __builtin_amdgcn_s_barrier();

  for (int kt = 0; kt < NT2; ++kt) {
    const bool stage = (kt + 2 < NT2);
    const int koff = (kt + 2) * 32;

    short8 bfr[4];
#pragma unroll
    for (int n = 0; n < 4; ++n)
      bfr[n] = *(const short8*)&b0[(16 + wn * 4 + n) * 512 + lane * 8];

#pragma unroll
    for (int q = 0; q < 2; ++q) {
      short8 afr[4];
#pragma unroll
      for (int m = 0; m < 4; ++m)
        afr[m] = *(const short8*)&b0[(wm * 8 + q * 4 + m) * 512 + lane * 8];

      if (stage) {
        gl16(gsrc[2 * q] + koff, b2 + ldso[2 * q]);
        gl16(gsrc[2 * q + 1] + koff, b2 + ldso[2 * q + 1]);
      }

      asm volatile("s_barrier" ::: "memory");

      __builtin_amdgcn_s_setprio(1);
#pragma unroll
      for (int m = 0; m < 4; ++m)
#pragma unroll
        for (int n = 0; n < 4; ++n)
          acc[q * 4 + m][n] =
              __builtin_amdgcn_mfma_f32_16x16x32_bf16(afr[m], bfr[n], acc[q * 4 + m][n], 0, 0, 0);
      __builtin_amdgcn_s_setprio(0);

      if (q == 1) {
        if (stage)
          asm volatile("s_waitcnt vmcnt(4)" ::: "memory");
        else
          asm volatile("s_waitcnt vmcnt(0)" ::: "memory");
      }
      asm volatile("s_barrier" ::: "memory");
    }

    ushort* tmp = b0; b0 = b1; b1 = b2; b2 = tmp;
  }

  const bool isx = (bn < DI);
  ushort* outp = isx ? xout : gateout;
  const int cbase = bn - (isx ? 0 : DI) + wn * 64;
#pragma unroll
  for (int mf = 0; mf < 8; ++mf)
#pragma unroll
    for (int nf = 0; nf < 4; ++nf) {
      int col = cbase + nf * 16 + r;
#pragma unroll
      for (int j = 0; j < 4; ++j) {
        int row = bm + wm * 128 + mf * 16 + hi * 4 + j;
        float v = acc[mf][nf][j];
        if (!isx) v = v / (1.f + __expf(-v));  // silu(res) fused
        outp[(size_t)row * DI + col] = f2b(v);
      }
    }
}

// ---------------- FUSED depthwise conv+SiLU + x_dbl split-K GEMM (KS=2) ------------------

__global__ __launch_bounds__(256) void xdbl_conv(const ushort* __restrict__ xp,
                                                 const float* __restrict__ cw,
                                                 const float* __restrict__ cb,
                                                 const ushort* __restrict__ wx,
                                                 ushort* __restrict__ xc,
                                                 float* __restrict__ xdp) {
  __shared__ ushort Af[32 * 544];  // 34 KB

  const int tid = threadIdx.x;
  const int row0 = blockIdx.x * 64;
  const int ks = blockIdx.y;       // 0..1

  const int lane = tid & 63, wid = tid >> 6;
  const int r = lane & 15, hi = lane >> 4;
  const int row0w = row0 + wid * 16;

  f32x4 acc[5];
#pragma unroll
  for (int n = 0; n < 5; ++n) acc[n] = f32x4{0.f, 0.f, 0.f, 0.f};

  const int rg = tid >> 5;          // 0..7 row-group (8 rows each)
  const int c8 = tid & 31;          // col8 0..31
  const int col_loc = c8 * 8;
  const int chunkc = col_loc >> 5;  // 0..7
  const int hi_w = (col_loc & 31) >> 3;

  for (int sl = 0; sl < 3; ++sl) {
    const int kbeg = ks * 768 + sl * 256;
    if (sl) __syncthreads();  // protect prior-slice Af reads

    {
      const int col = kbeg + col_loc;
      float4 cwv[8];
      float cbv[8];
#pragma unroll
      for (int e = 0; e < 8; ++e) {
        cwv[e] = *(const float4*)(cw + (size_t)(col + e) * 4);
        cbv[e] = cb[col + e];
      }
      short8 z8 = {0, 0, 0, 0, 0, 0, 0, 0};
#pragma unroll
      for (int j = 0; j < 8; ++j) {
        int row = row0 + rg * 8 + j;
        int l = row & (L_SZ - 1);
        const ushort* base = xp + (size_t)row * DI + col;
        short8 x0 = *(const short8*)base;
        short8 xm1 = (l >= 1) ? *(const short8*)(base - DI) : z8;
        short8 xm2 = (l >= 2) ? *(const short8*)(base - 2 * DI) : z8;
        short8 xm3 = (l >= 3) ? *(const short8*)(base - 3 * DI) : z8;
        short8 o;
#pragma unroll
        for (int e = 0; e < 8; ++e) {
          float4 w = cwv[e];
          float a = cbv[e] + w.x * b2f((ushort)xm3[e]) + w.y * b2f((ushort)xm2[e]) +
                    w.z * b2f((ushort)xm1[e]) + w.w * b2f((ushort)x0[e]);
          o[e] = (short)f2b(a / (1.f + __expf(-a)));
        }
        *(short8*)(xc + (size_t)row * DI + col) = o;
        int row_loc = rg * 8 + j;
        int chunk = (row_loc >> 4) * 8 + chunkc;
        int lane_t = (hi_w << 4) | (row_loc & 15);
        int slot = lane_t ^ (chunk & 7);
        *(short8*)&Af[chunk * 544 + slot * 8] = o;
      }
    }
    __syncthreads();

#pragma unroll
    for (int k0 = 0; k0 < 8; ++k0) {
      int chunk = wid * 8 + k0;
      short8 a = *(const short8*)&Af[chunk * 544 + ((lane ^ (chunk & 7)) * 8)];
      const int kk = kbeg + k0 * 32;
#pragma unroll
      for (int n = 0; n < 5; ++n) {
        short8 b = *(const short8*)(wx + (size_t)(n * 16 + r) * DI + kk + hi * 8);
        acc[n] = __builtin_amdgcn_mfma_f32_16x16x32_bf16(a, b, acc[n], 0, 0, 0);
      }
    }
  }

  float* op = xdp + (size_t)ks * M_SZ * 80;
#pragma unroll
  for (int n = 0; n < 5; ++n)
#pragma unroll
    for (int j = 0; j < 4; ++j)
      op[(size_t)(row0w + hi * 4 + j) * 80 + n * 16 + r] = acc[n][j];
}

// ---------------- dt = softplus(x_dbl[:, :48] @ W_dt^T + b_dt) -> fp16 -------------------

__device__ __forceinline__ short8 pack8f(const float* p) {
  short8 v;
#pragma unroll
  for (int i = 0; i < 8; ++i) v[i] = (short)f2b(p[i]);
  return v;
}

__global__ __launch_bounds__(256) void dt_gemm(const float* __restrict__ xdp,
                                               const ushort* __restrict__ wdtp,
                                               const float* __restrict__ bdt,
                                               ushort* __restrict__ dt) {
  int wave = blockIdx.x * 4 + (threadIdx.x >> 6);
  int lane = threadIdx.x & 63;
  int r = lane & 15, hi = lane >> 4;
  int row0 = wave * 16;

  const float* p0 = xdp + (size_t)(row0 + r) * 80 + hi * 8;
  const float* p1 = p0 + (size_t)M_SZ * 80;

  float atmp[8];
  float4 q0 = *(const float4*)p0, q1 = *(const float4*)(p0 + 4);
  float4 s0 = *(const float4*)p1, s1 = *(const float4*)(p1 + 4);
  atmp[0] = q0.x + s0.x; atmp[1] = q0.y + s0.y; atmp[2] = q0.z + s0.z; atmp[3] = q0.w + s0.w;
  atmp[4] = q1.x + s1.x; atmp[5] = q1.y + s1.y; atmp[6] = q1.z + s1.z; atmp[7] = q1.w + s1.w;
  short8 a0 = pack8f(atmp);
  short8 a1 = {0, 0, 0, 0, 0, 0, 0, 0};
  if (hi < 2) {
    const float* q0p = xdp + (size_t)(row0 + r) * 80 + 32 + hi * 8;
    const float* q1p = q0p + (size_t)M_SZ * 80;
    float4 u0 = *(const float4*)q0p, u1 = *(const float4*)(q0p + 4);
    float4 v0 = *(const float4*)q1p, v1 = *(const float4*)(q1p + 4);
    atmp[0] = u0.x + v0.x; atmp[1] = u0.y + v0.y; atmp[2] = u0.z + v0.z; atmp[3] = u0.w + v0.w;
    atmp[4] = u1.x + v1.x; atmp[5] = u1.y + v1.y; atmp[6] = u1.z + v1.z; atmp[7] = u1.w + v1.w;
    a1 = pack8f(atmp);
  }

  for (int nb = blockIdx.y * 6; nb < blockIdx.y * 6 + 6; ++nb) {
    int c0 = nb * 64;
    f32x4 acc[4];
#pragma unroll
    for (int n = 0; n < 4; ++n) acc[n] = f32x4{0.f, 0.f, 0.f, 0.f};
#pragma unroll
    for (int n = 0; n < 4; ++n) {
      const ushort* wp = wdtp + (size_t)(c0 + n * 16 + r) * 64;
      short8 b0 = *(const short8*)(wp + hi * 8);
      short8 b1 = *(const short8*)(wp + 32 + hi * 8);
      acc[n] = __builtin_amdgcn_mfma_f32_16x16x32_bf16(a0, b0, acc[n], 0, 0, 0);
      acc[n] = __builtin_amdgcn_mfma_f32_16x16x32_bf16(a1, b1, acc[n], 0, 0, 0);
    }
#pragma unroll
    for (int n = 0; n < 4; ++n)
#pragma unroll
      for (int j = 0; j < 4; ++j) {
        int col = c0 + n * 16 + r;
        float z = acc[n][j] + bdt[col];
        float sp = (z > 20.f) ? z : __logf(1.f + __expf(z));
        dt[(size_t)(row0 + hi * 4 + j) * DI + col] = f2h(sp);
      }
  }
}

// ---------------- chunked selective scan (NC=64, depth-2 prefetch, pk math) --------------

__global__ __launch_bounds__(256) void scan_pass1(const ushort* __restrict__ dt,
                                                  const ushort* __restrict__ xc,
                                                  const float* __restrict__ xdp,
                                                  const float* __restrict__ A_log,
                                                  float* __restrict__ hend,
                                                  float* __restrict__ sumdt) {
  const int d = blockIdx.x * 256 + threadIdx.x;
  const int c = blockIdx.y, b = blockIdx.z;
  const int t0 = c * TC;

  __shared__ float Bs[TC * 16];
  for (int i = threadIdx.x; i < TC * 16; i += 256) {
    int tt = i >> 4, s = i & 15;
    size_t row = ((size_t)(b * L_SZ + t0 + tt)) * 80 + DR + s;
    Bs[i] = xdp[row] + xdp[(size_t)M_SZ * 80 + row];
  }

  f32x2 a2[8];
  const float4* al4 = (const float4*)(A_log + (size_t)d * DS);
#pragma unroll
  for (int q = 0; q < 4; ++q) {
    float4 v = al4[q];
    a2[2 * q] = f32x2{-__expf(v.x) * L2E, -__expf(v.y) * L2E};
    a2[2 * q + 1] = f32x2{-__expf(v.z) * L2E, -__expf(v.w) * L2E};
  }

  __syncthreads();

  f32x2 h2[8];
#pragma unroll
  for (int q = 0; q < 8; ++q) h2[q] = f32x2{0.f, 0.f};
  float sd = 0.f;

  const ushort* dtp = dt + ((size_t)b * L_SZ + t0) * DI + d;
  const ushort* xp = xc + ((size_t)b * L_SZ + t0) * DI + d;

  ushort dt0 = dtp[0], dt1 = dtp[DI];
  ushort xu0 = xp[0], xu1 = xp[DI];
  dtp += 2 * (size_t)DI; xp += 2 * (size_t)DI;
  const f32x4* bp4 = (const f32x4*)Bs;
#pragma unroll 2
  for (int tt = 0; tt < TC; ++tt) {
    ushort dtu = dt0, xu = xu0;
    dt0 = dt1; xu0 = xu1;
    dt1 = *dtp; xu1 = *xp;
    dtp += DI; xp += DI;
    float dtv = h2f(dtu);
    float xv = b2f(xu);
    sd += dtv;
    float dx = dtv * xv;
    f32x2 dts = f32x2{dtv, dtv};
    f32x2 dxs = f32x2{dx, dx};
#pragma unroll
    for (int q4 = 0; q4 < 4; ++q4) {
      f32x4 bq = bp4[q4];
#pragma unroll
      for (int hq = 0; hq < 2; ++hq) {
        int q = q4 * 2 + hq;
        f32x2 bv = f32x2{bq[2 * hq], bq[2 * hq + 1]};
        f32x2 arg, t2;
        asm("v_pk_mul_f32 %0, %1, %2" : "=v"(arg) : "v"(dts), "v"(a2[q]));
        float e0, e1;
        asm("v_exp_f32 %0, %1" : "=v"(e0) : "v"(arg[0]));
        asm("v_exp_f32 %0, %1" : "=v"(e1) : "v"(arg[1]));
        asm("v_pk_mul_f32 %0, %1, %2" : "=v"(t2) : "v"(dxs), "v"(bv));
        h2[q][0] = __builtin_fmaf(e0, h2[q][0], t2[0]);
        h2[q][1] = __builtin_fmaf(e1, h2[q][1], t2[1]);
      }
    }
    bp4 += 4;
  }

  const size_t ch = (size_t)b * DI + d;
  sumdt[ch * NC + c] = sd;
  f32x2* hp = (f32x2*)&hend[((size_t)c * CH + ch) * 16];
#pragma unroll
  for (int q = 0; q < 8; ++q) hp[q] = h2[q];
}

// pass2: in-place hbuf (reads hend[c], overwrites with hstart[c])

__global__ __launch_bounds__(256) void scan_pass2(const float* __restrict__ A_log,
                                                  const float* __restrict__ sumdt,
                                                  float* __restrict__ hbuf) {
  int idx = blockIdx.x * 256 + threadIdx.x;
  int ch = idx >> 4, s = idx & 15;
  int d = ch % DI;
  float A = -__expf(A_log[d * DS + s]);
  float h = 0.f;
  for (int c = 0; c < NC; ++c) {
    float* p = &hbuf[((size_t)c * CH + ch) * 16 + s];
    float he = *p;
    *p = h;
    float sd = sumdt[(size_t)ch * NC + c];
    h = __expf(A * sd) * h + he;
  }
}

__global__ __launch_bounds__(256) void scan_pass3(const ushort* __restrict__ dt,
                                                  const ushort* __restrict__ xc,
                                                  const float* __restrict__ xdp,
                                                  const ushort* __restrict__ gateb,
                                                  const float* __restrict__ A_log,
                                                  const float* __restrict__ Dp,
                                                  const float* __restrict__ hstart,
                                                  float* __restrict__ out) {
  const int d = blockIdx.x * 256 + threadIdx.x;
  const int c = blockIdx.y, b = blockIdx.z;
  const int t0 = c * TC;

  __shared__ float Bs[TC * 16];
  __shared__ float Cs[TC * 16];
  for (int i = threadIdx.x; i < TC * 16; i += 256) {
    int tt = i >> 4, s = i & 15;
    size_t row = ((size_t)(b * L_SZ + t0 + tt)) * 80;
    Bs[i] = xdp[row + DR + s] + xdp[(size_t)M_SZ * 80 + row + DR + s];
    Cs[i] = xdp[row + DR + DS + s] + xdp[(size_t)M_SZ * 80 + row + DR + DS + s];
  }

  f32x2 a2[8];
  const float4* al4 = (const float4*)(A_log + (size_t)d * DS);
#pragma unroll
  for (int q = 0; q < 4; ++q) {
    float4 v = al4[q];
    a2[2 * q] = f32x2{-__expf(v.x) * L2E, -__expf(v.y) * L2E};
    a2[2 * q + 1] = f32x2{-__expf(v.z) * L2E, -__expf(v.w) * L2E};
  }
  const float Dpv = Dp[d];

  const size_t ch = (size_t)b * DI + d;
  f32x2 h2[8];
  const f32x2* hp = (const f32x2*)&hstart[((size_t)c * CH + ch) * 16];
#pragma unroll
  for (int q = 0; q < 8; ++q) h2[q] = hp[q];

  __syncthreads();

  const ushort* dtp = dt + ((size_t)b * L_SZ + t0) * DI + d;
  const ushort* xp = xc + ((size_t)b * L_SZ + t0) * DI + d;
  const ushort* gp = gateb + ((size_t)b * L_SZ + t0) * DI + d;
  float* op = out + ((size_t)b * L_SZ + t0) * DI + d;

  ushort dt0 = dtp[0], dt1 = dtp[DI];
  ushort xu0 = xp[0], xu1 = xp[DI];
  ushort gu0 = gp[0], gu1 = gp[DI];
  dtp += 2 * (size_t)DI; xp += 2 * (size_t)DI; gp += 2 * (size_t)DI;
  const f32x4* bp4 = (const f32x4*)Bs;
  const f32x4* cp4 = (const f32x4*)Cs;
#pragma unroll 2
  for (int tt = 0; tt < TC; ++tt) {
    ushort dtu = dt0, xu = xu0, gu = gu0;
    dt0 = dt1; xu0 = xu1; gu0 = gu1;
    dt1 = *dtp; xu1 = *xp; gu1 = *gp;
    dtp += DI; xp += DI; gp += DI;
    float dtv = h2f(dtu);
    float xv = b2f(xu);
    float gv = b2f(gu);
    float dx = dtv * xv;
    f32x2 dts = f32x2{dtv, dtv};
    f32x2 dxs = f32x2{dx, dx};
    f32x2 ya = f32x2{0.f, 0.f}, yb = f32x2{0.f, 0.f};
#pragma unroll
    for (int q4 = 0; q4 < 4; ++q4) {
      f32x4 bq = bp4[q4];
      f32x4 cq = cp4[q4];
#pragma unroll
      for (int hq = 0; hq < 2; ++hq) {
        int q = q4 * 2 + hq;
        f32x2 bv = f32x2{bq[2 * hq], bq[2 * hq + 1]};
        f32x2 cv = f32x2{cq[2 * hq], cq[2 * hq + 1]};
        f32x2 arg, t2;
        asm("v_pk_mul_f32 %0, %1, %2" : "=v"(arg) : "v"(dts), "v"(a2[q]));
        float e0, e1;
        asm("v_exp_f32 %0, %1" : "=v"(e0) : "v"(arg[0]));
        asm("v_exp_f32 %0, %1" : "=v"(e1) : "v"(arg[1]));
        asm("v_pk_mul_f32 %0, %1, %2" : "=v"(t2) : "v"(dxs), "v"(bv));
        h2[q][0] = __builtin_fmaf(e0, h2[q][0], t2[0]);
        h2[q][1] = __builtin_fmaf(e1, h2[q][1], t2[1]);
        if (hq)
          asm("v_pk_fma_f32 %0, %1, %2, %0" : "+v"(yb) : "v"(h2[q]), "v"(cv));
        else
          asm("v_pk_fma_f32 %0, %1, %2, %0" : "+v"(ya) : "v"(h2[q]), "v"(cv));
      }
    }
    bp4 += 4; cp4 += 4;
    float y = (ya[0] + ya[1]) + (yb[0] + yb[1]);
    op[0] = (y + xv * Dpv) * gv;
    op += DI;
  }
}

// ---------------- launch ----------------

extern "C" void kernel_launch(void* const* d_in, const int* in_sizes, int n_in,
                              void* d_out, int out_size, void* d_ws, size_t ws_size,
                              hipStream_t stream) {
  const float* hs     = (const float*)d_in[0];
  const float* W_in   = (const float*)d_in[1];
  const float* conv_w = (const float*)d_in[2];
  const float* conv_b = (const float*)d_in[3];
  const float* W_x    = (const float*)d_in[4];
  const float* W_dt   = (const float*)d_in[5];
  const float* b_dt   = (const float*)d_in[6];
  const float* A_log  = (const float*)d_in[7];
  const float* D_par  = (const float*)d_in[8];
  float* out = (float*)d_out;
  char* ws = (char*)d_ws;

  size_t o = 0;
  ushort* A1   = (ushort*)(ws + o); o += (size_t)M_SZ * DM * 2;        // 25.2 MB
  ushort* Wt1  = (ushort*)(ws + o); o += (size_t)N1 * DM * 2;          // 4.7 MB
  ushort* xpre = (ushort*)(ws + o); o += (size_t)M_SZ * DI * 2;        // 50.3 MB
  ushort* gate = (ushort*)(ws + o); o += (size_t)M_SZ * DI * 2;        // 50.3 MB (silu(res))
  ushort* xcv  = (ushort*)(ws + o); o += (size_t)M_SZ * DI * 2;        // 50.3 MB
  ushort* dtb  = (ushort*)(ws + o); o += (size_t)M_SZ * DI * 2;        // 50.3 MB (fp16)
  float*  xdp  = (float*)(ws + o);  o += (size_t)KS * M_SZ * 80 * 4;   // 10.5 MB
  ushort* Wxb  = (ushort*)(ws + o); o += (size_t)80 * DI * 2;          // 0.25 MB
  ushort* Wdtp = (ushort*)(ws + o); o += (size_t)DI * 64 * 2;          // 0.2 MB
  if (ws_size < o) return;

  // scan scratch aliases the dead A1/Wt1/xpre region (53.4 MB < 80.2 MB)
  float* hbuf  = (float*)(ws + 0);
  float* sumdt = (float*)(ws + (size_t)NC * CH * 16 * 4);

  const int nprep = M_SZ * DM / 4 + 3072 * 96 + 80 * DI + DI * 64;
  prep_all<<<dim3((nprep + 255) / 256), dim3(256), 0, stream>>>(
      (const float4*)hs, W_in, W_x, W_dt, (ushort4*)A1, Wt1, Wxb, Wdtp);

  gemm_xz<<<dim3((M_SZ / 256) * (N1 / 256)), dim3(512), 0, stream>>>(A1, Wt1, xpre, gate);

  xdbl_conv<<<dim3(M_SZ / 64, KS), dim3(256), 0, stream>>>(xpre, conv_w, conv_b, Wxb,
                                                           xcv, xdp);

  dt_gemm<<<dim3(M_SZ / 64, 4), dim3(256), 0, stream>>>(xdp, Wdtp, b_dt, dtb);

  scan_pass1<<<dim3(DI / 256, NC, B_SZ), dim3(256), 0, stream>>>(dtb, xcv, xdp, A_log, hbuf, sumdt);
  scan_pass2<<<dim3(CH * 16 / 256), dim3(256), 0, stream>>>(A_log, sumdt, hbuf);
  scan_pass3<<<dim3(DI / 256, NC, B_SZ), dim3(256), 0, stream>>>(dtb, xcv, xdp, gate,
                                                                 A_log, D_par, hbuf, out);
}